// Round 2
// baseline (775.620 us; speedup 1.0000x reference)
//
#include <hip/hip_runtime.h>
#include <math.h>

#define Bsz 8
#define NBOX 100
#define Hh 96
#define Ww 96
#define Dd 768
#define KK 10
#define C1 512
#define C2 256
#define C3 117

// workspace layout (in floats)
#define OFF_SELIDX 0                  // 160 ints
#define OFF_OK     160                // 160 floats
#define OFF_INV    320                // 160 floats
#define OFF_POOLED 512                // 160*768 floats
#define OFF_PART   (512 + 160*Dd)     // 160*512 floats

// ---------------------------------------------------------------------------
// Kernel A: per-(batch,category) serial top-K (matches jax.lax.top_k:
// descending values, ties -> lower index first).
// ---------------------------------------------------------------------------
__global__ void topk_kernel(const int* __restrict__ labels,
                            const float* __restrict__ scores,
                            const int* __restrict__ boxes,
                            int* __restrict__ sel_idx,
                            float* __restrict__ sel_ok,
                            float* __restrict__ inv_area) {
    __shared__ float arr[16][NBOX];
    int t = threadIdx.x;
    if (t >= 16) return;
    int b = t >> 1, c = t & 1;
    for (int n = 0; n < NBOX; ++n) {
        int lab = labels[b * NBOX + n];
        bool is_h = (lab == 1);
        bool keep = (c == 0) ? is_h : !is_h;
        arr[t][n] = keep ? scores[b * NBOX + n] : -1e30f;
    }
    for (int k = 0; k < KK; ++k) {
        float bv = -INFINITY; int bi = 0;
        for (int n = 0; n < NBOX; ++n) {
            float v = arr[t][n];
            if (v > bv) { bv = v; bi = n; }   // strict > : first max wins (lowest idx)
        }
        arr[t][bi] = -INFINITY;
        int s = (b * 2 + c) * KK + k;
        sel_idx[s] = bi;
        sel_ok[s] = (bv > -5e29f) ? 1.0f : 0.0f;
        const int* bx = boxes + (b * NBOX + bi) * 4;
        float area = (float)((bx[3] - bx[1]) * (bx[2] - bx[0]));
        inv_area[s] = 1.0f / area;
    }
}

// ---------------------------------------------------------------------------
// Kernel B: direct box-sum pooling of ONLY the 160 selected boxes.
// grid (160 boxes, 1, 12 row-chunks of 8); 192 threads each own one float4
// channel group (768/4). atomicAdd accumulates row-chunk partials into
// pre-zeroed `pooled`.
// ---------------------------------------------------------------------------
__global__ void pool_kernel(const float* __restrict__ feat,
                            const int* __restrict__ boxes,
                            const int* __restrict__ sel_idx,
                            float* __restrict__ pooled) {
    int s = blockIdx.x;
    int b = s / (2 * KK);
    int n = sel_idx[s];
    const int* bx = boxes + (b * NBOX + n) * 4;
    int x1 = bx[0], y1 = bx[1], x2 = bx[2], y2 = bx[3];
    int y0 = y1 + blockIdx.z * 8;
    if (y0 >= y2) return;
    int ye = min(y0 + 8, y2);
    int d4 = threadIdx.x;                       // 0..191
    const float4* feat4 = (const float4*)feat;  // [B,h,w,192] float4s
    float4 acc = make_float4(0.f, 0.f, 0.f, 0.f);
    for (int y = y0; y < ye; ++y) {
        const float4* row = feat4 + ((size_t)(b * Hh + y) * Ww) * (Dd / 4) + d4;
        for (int x = x1; x < x2; ++x) {
            float4 v = row[(size_t)x * (Dd / 4)];
            acc.x += v.x; acc.y += v.y; acc.z += v.z; acc.w += v.w;
        }
    }
    float* dst = &pooled[(size_t)s * Dd + d4 * 4];
    atomicAdd(dst + 0, acc.x);
    atomicAdd(dst + 1, acc.y);
    atomicAdd(dst + 2, acc.z);
    atomicAdd(dst + 3, acc.w);
}

// ---------------------------------------------------------------------------
// Kernel C: per-slot half-projection through W1 (layer-1 decomposes over the
// concat: pair@W1 = h@W1_top + o@W1_bot). 16 slot-groups (10 slots, same
// category) x 2 output halves; W1 half read once per block.
// ---------------------------------------------------------------------------
__global__ void part_kernel(const float* __restrict__ pooled,
                            const float* __restrict__ inv_area,
                            const float* __restrict__ W1,
                            float* __restrict__ part) {
    __shared__ float pv[KK * Dd];                 // 30 KB: 10 slots' raw sums
    int sg = blockIdx.x;                          // 0..15  (= b*2 + c)
    int o = blockIdx.y * 256 + threadIdx.x;       // 0..511
    for (int idx = threadIdx.x; idx < KK * Dd; idx += 256)
        pv[idx] = pooled[(size_t)sg * KK * Dd + idx];
    __syncthreads();
    int c = sg & 1;
    const float* Wp = W1 + (size_t)(c * Dd) * C1 + o;
    float acc[KK];
#pragma unroll
    for (int j = 0; j < KK; ++j) acc[j] = 0.f;
    for (int d = 0; d < Dd; ++d) {
        float w = Wp[(size_t)d * C1];
#pragma unroll
        for (int j = 0; j < KK; ++j) acc[j] += pv[j * Dd + d] * w;
    }
    for (int j = 0; j < KK; ++j)
        part[(size_t)(sg * KK + j) * C1 + o] = acc[j] * inv_area[sg * KK + j];
}

// ---------------------------------------------------------------------------
// Kernel D: fused layers 1(sum+bias+relu) -> 2 -> 3 + valid mask.
// One block per (b, human i); 10 object pairs share W2/W3 reads.
// ---------------------------------------------------------------------------
__global__ void mlp_kernel(const float* __restrict__ part,
                           const float* __restrict__ sel_ok,
                           const float* __restrict__ b1,
                           const float* __restrict__ W2,
                           const float* __restrict__ b2,
                           const float* __restrict__ W3,
                           const float* __restrict__ b3,
                           float* __restrict__ out) {
    __shared__ float x1s[KK][C1];   // 20 KB
    __shared__ float x2s[KK][C2];   // 10 KB
    int blk = blockIdx.x;
    int b = blk / KK, i = blk % KK;
    const float* hp = part + (size_t)(b * 2 * KK + i) * C1;       // human slot i
    const float* op = part + (size_t)(b * 2 * KK + KK) * C1;      // object slots base
    int tid = threadIdx.x;

    // layer 1: relu(hpart + opart + b1)
    for (int o = tid; o < C1; o += 256) {
        float h = hp[o] + b1[o];
#pragma unroll
        for (int j = 0; j < KK; ++j) {
            float v = h + op[(size_t)j * C1 + o];
            x1s[j][o] = v > 0.f ? v : 0.f;
        }
    }
    __syncthreads();

    // layer 2: 512 -> 256, relu
    {
        int o2 = tid;
        float acc[KK];
        float bb = b2[o2];
#pragma unroll
        for (int j = 0; j < KK; ++j) acc[j] = bb;
        for (int k = 0; k < C1; ++k) {
            float w = W2[(size_t)k * C2 + o2];
#pragma unroll
            for (int j = 0; j < KK; ++j) acc[j] += x1s[j][k] * w;
        }
#pragma unroll
        for (int j = 0; j < KK; ++j) x2s[j][o2] = acc[j] > 0.f ? acc[j] : 0.f;
    }
    __syncthreads();

    // layer 3: 256 -> 117, mask, store
    float* rel = out;
    float* valid = out + (size_t)Bsz * KK * KK * C3;
    float hok = sel_ok[b * 2 * KK + i];
    if (tid < C3) {
        float acc[KK];
        float bb = b3[tid];
#pragma unroll
        for (int j = 0; j < KK; ++j) acc[j] = bb;
        for (int k = 0; k < C2; ++k) {
            float w = W3[(size_t)k * C3 + tid];
#pragma unroll
            for (int j = 0; j < KK; ++j) acc[j] += x2s[j][k] * w;
        }
        for (int j = 0; j < KK; ++j) {
            float v = hok * sel_ok[b * 2 * KK + KK + j];
            rel[((size_t)(b * KK + i) * KK + j) * C3 + tid] = acc[j] * v;
        }
    }
    if (tid < KK) {
        valid[(size_t)(b * KK + i) * KK + tid] = hok * sel_ok[b * 2 * KK + KK + tid];
    }
}

// ---------------------------------------------------------------------------
extern "C" void kernel_launch(void* const* d_in, const int* in_sizes, int n_in,
                              void* d_out, int out_size, void* d_ws, size_t ws_size,
                              hipStream_t stream) {
    const float* feat   = (const float*)d_in[0];
    const int*   boxes  = (const int*)d_in[1];
    const int*   labels = (const int*)d_in[2];
    const float* scores = (const float*)d_in[3];
    const float* W1     = (const float*)d_in[4];
    const float* b1     = (const float*)d_in[5];
    const float* W2     = (const float*)d_in[6];
    const float* b2     = (const float*)d_in[7];
    const float* W3     = (const float*)d_in[8];
    const float* b3     = (const float*)d_in[9];

    float* ws       = (float*)d_ws;
    int*   sel_idx  = (int*)(ws + OFF_SELIDX);
    float* sel_ok   = ws + OFF_OK;
    float* inv_area = ws + OFF_INV;
    float* pooled   = ws + OFF_POOLED;
    float* part     = ws + OFF_PART;

    hipMemsetAsync(pooled, 0, sizeof(float) * 160 * Dd, stream);
    topk_kernel<<<1, 64, 0, stream>>>(labels, scores, boxes, sel_idx, sel_ok, inv_area);
    pool_kernel<<<dim3(160, 1, 12), 192, 0, stream>>>(feat, boxes, sel_idx, pooled);
    part_kernel<<<dim3(16, 2), 256, 0, stream>>>(pooled, inv_area, W1, part);
    mlp_kernel<<<Bsz * KK, 256, 0, stream>>>(part, sel_ok, b1, W2, b2, W3, b3, (float*)d_out);
}

// Round 4
// 584.227 us; speedup vs baseline: 1.3276x; 1.3276x over previous
//
#include <hip/hip_runtime.h>
#include <math.h>

#define Bsz 8
#define NBOX 100
#define Hh 96
#define Ww 96
#define Dd 768
#define KK 10
#define C1 512
#define C2 256
#define C3 117

// workspace layout (in floats)
#define OFF_SELIDX 0                  // 160 ints
#define OFF_OK     160                // 160 floats
#define OFF_INV    320                // 160 floats
#define OFF_POOLED 512                // 160*768 floats
#define OFF_PART   (512 + 160*Dd)     // 160*512 floats

// ---------------------------------------------------------------------------
// Kernel A: top-K per (batch, category). Cooperative 64-thread fill of the
// masked score array (coalesced global loads), then 16 independent serial
// selectors working purely in LDS (matches jax.lax.top_k tie-break: lowest
// index first).
// ---------------------------------------------------------------------------
__global__ void topk_kernel(const int* __restrict__ labels,
                            const float* __restrict__ scores,
                            const int* __restrict__ boxes,
                            int* __restrict__ sel_idx,
                            float* __restrict__ sel_ok,
                            float* __restrict__ inv_area) {
    __shared__ float arr[16][NBOX];
    int tid = threadIdx.x;
    // fill: 16 rows x 100 entries = 1600 slots, 64 threads
    for (int idx = tid; idx < 16 * NBOX; idx += 64) {
        int t = idx / NBOX, n = idx % NBOX;
        int b = t >> 1, c = t & 1;
        int lab = labels[b * NBOX + n];
        bool is_h = (lab == 1);
        bool keep = (c == 0) ? is_h : !is_h;
        arr[t][n] = keep ? scores[b * NBOX + n] : -1e30f;
    }
    __syncthreads();
    if (tid >= 16) return;
    int t = tid, b = t >> 1, c = t & 1;
    for (int k = 0; k < KK; ++k) {
        float bv = -INFINITY; int bi = 0;
        for (int n = 0; n < NBOX; ++n) {
            float v = arr[t][n];
            if (v > bv) { bv = v; bi = n; }   // strict > : first max wins (lowest idx)
        }
        arr[t][bi] = -INFINITY;
        int s = (b * 2 + c) * KK + k;
        sel_idx[s] = bi;
        sel_ok[s] = (bv > -5e29f) ? 1.0f : 0.0f;
        const int* bx = boxes + (b * NBOX + bi) * 4;
        float area = (float)((bx[3] - bx[1]) * (bx[2] - bx[0]));
        inv_area[s] = 1.0f / area;
    }
}

// ---------------------------------------------------------------------------
// Kernel B: direct box-sum pooling of ONLY the 160 selected boxes.
// One block per (box, row): grid (160, 96); rows outside the box exit
// immediately. 192 threads each own one float4 channel group; the x-loop is
// 4-way unrolled with independent accumulators (16 outstanding loads).
// atomicAdd accumulates per-row partials into pre-zeroed `pooled`.
// ---------------------------------------------------------------------------
__global__ void pool_kernel(const float* __restrict__ feat,
                            const int* __restrict__ boxes,
                            const int* __restrict__ sel_idx,
                            float* __restrict__ pooled) {
    int s = blockIdx.x;
    int y = blockIdx.y;
    int b = s / (2 * KK);
    int n = sel_idx[s];
    const int* bx = boxes + (b * NBOX + n) * 4;
    int x1 = bx[0], y1 = bx[1], x2 = bx[2], y2 = bx[3];
    if (y < y1 || y >= y2) return;
    int d4 = threadIdx.x;                       // 0..191
    const float4* rowp = (const float4*)feat
        + ((size_t)(b * Hh + y) * Ww) * (Dd / 4) + d4;
    float4 a0 = make_float4(0.f, 0.f, 0.f, 0.f);
    float4 a1 = a0, a2 = a0, a3 = a0;
    int x = x1;
    for (; x + 4 <= x2; x += 4) {
        float4 v0 = rowp[(size_t)(x + 0) * (Dd / 4)];
        float4 v1 = rowp[(size_t)(x + 1) * (Dd / 4)];
        float4 v2 = rowp[(size_t)(x + 2) * (Dd / 4)];
        float4 v3 = rowp[(size_t)(x + 3) * (Dd / 4)];
        a0.x += v0.x; a0.y += v0.y; a0.z += v0.z; a0.w += v0.w;
        a1.x += v1.x; a1.y += v1.y; a1.z += v1.z; a1.w += v1.w;
        a2.x += v2.x; a2.y += v2.y; a2.z += v2.z; a2.w += v2.w;
        a3.x += v3.x; a3.y += v3.y; a3.z += v3.z; a3.w += v3.w;
    }
    for (; x < x2; ++x) {
        float4 v0 = rowp[(size_t)x * (Dd / 4)];
        a0.x += v0.x; a0.y += v0.y; a0.z += v0.z; a0.w += v0.w;
    }
    a0.x += a1.x + a2.x + a3.x;
    a0.y += a1.y + a2.y + a3.y;
    a0.z += a1.z + a2.z + a3.z;
    a0.w += a1.w + a2.w + a3.w;
    float* dst = &pooled[(size_t)s * Dd + d4 * 4];
    atomicAdd(dst + 0, a0.x);
    atomicAdd(dst + 1, a0.y);
    atomicAdd(dst + 2, a0.z);
    atomicAdd(dst + 3, a0.w);
}

// ---------------------------------------------------------------------------
// Kernel C: per-slot half-projection through W1 (layer-1 decomposes over the
// concat: pair@W1 = h@W1_top + o@W1_bot). 16 slot-groups (10 slots, same
// category) x 2 output halves; W1 half read once per block.
// ---------------------------------------------------------------------------
__global__ void part_kernel(const float* __restrict__ pooled,
                            const float* __restrict__ inv_area,
                            const float* __restrict__ W1,
                            float* __restrict__ part) {
    __shared__ float pv[KK * Dd];                 // 30 KB: 10 slots' raw sums
    int sg = blockIdx.x;                          // 0..15  (= b*2 + c)
    int o = blockIdx.y * 256 + threadIdx.x;       // 0..511
    for (int idx = threadIdx.x; idx < KK * Dd; idx += 256)
        pv[idx] = pooled[(size_t)sg * KK * Dd + idx];
    __syncthreads();
    int c = sg & 1;
    const float* Wp = W1 + (size_t)(c * Dd) * C1 + o;
    float acc[KK];
#pragma unroll
    for (int j = 0; j < KK; ++j) acc[j] = 0.f;
    for (int d = 0; d < Dd; ++d) {
        float w = Wp[(size_t)d * C1];
#pragma unroll
        for (int j = 0; j < KK; ++j) acc[j] += pv[j * Dd + d] * w;
    }
    for (int j = 0; j < KK; ++j)
        part[(size_t)(sg * KK + j) * C1 + o] = acc[j] * inv_area[sg * KK + j];
}

// ---------------------------------------------------------------------------
// Kernel D: fused layers 1(sum+bias+relu) -> 2 -> 3 + valid mask.
// One block per (b, human i); 10 object pairs share W2/W3 reads.
// ---------------------------------------------------------------------------
__global__ void mlp_kernel(const float* __restrict__ part,
                           const float* __restrict__ sel_ok,
                           const float* __restrict__ b1,
                           const float* __restrict__ W2,
                           const float* __restrict__ b2,
                           const float* __restrict__ W3,
                           const float* __restrict__ b3,
                           float* __restrict__ out) {
    __shared__ float x1s[KK][C1];   // 20 KB
    __shared__ float x2s[KK][C2];   // 10 KB
    int blk = blockIdx.x;
    int b = blk / KK, i = blk % KK;
    const float* hp = part + (size_t)(b * 2 * KK + i) * C1;       // human slot i
    const float* op = part + (size_t)(b * 2 * KK + KK) * C1;      // object slots base
    int tid = threadIdx.x;

    // layer 1: relu(hpart + opart + b1)
    for (int o = tid; o < C1; o += 256) {
        float h = hp[o] + b1[o];
#pragma unroll
        for (int j = 0; j < KK; ++j) {
            float v = h + op[(size_t)j * C1 + o];
            x1s[j][o] = v > 0.f ? v : 0.f;
        }
    }
    __syncthreads();

    // layer 2: 512 -> 256, relu
    {
        int o2 = tid;
        float acc[KK];
        float bb = b2[o2];
#pragma unroll
        for (int j = 0; j < KK; ++j) acc[j] = bb;
        for (int k = 0; k < C1; ++k) {
            float w = W2[(size_t)k * C2 + o2];
#pragma unroll
            for (int j = 0; j < KK; ++j) acc[j] += x1s[j][k] * w;
        }
#pragma unroll
        for (int j = 0; j < KK; ++j) x2s[j][o2] = acc[j] > 0.f ? acc[j] : 0.f;
    }
    __syncthreads();

    // layer 3: 256 -> 117, mask, store
    float* rel = out;
    float* valid = out + (size_t)Bsz * KK * KK * C3;
    float hok = sel_ok[b * 2 * KK + i];
    if (tid < C3) {
        float acc[KK];
        float bb = b3[tid];
#pragma unroll
        for (int j = 0; j < KK; ++j) acc[j] = bb;
        for (int k = 0; k < C2; ++k) {
            float w = W3[(size_t)k * C3 + tid];
#pragma unroll
            for (int j = 0; j < KK; ++j) acc[j] += x2s[j][k] * w;
        }
        for (int j = 0; j < KK; ++j) {
            float v = hok * sel_ok[b * 2 * KK + KK + j];
            rel[((size_t)(b * KK + i) * KK + j) * C3 + tid] = acc[j] * v;
        }
    }
    if (tid < KK) {
        valid[(size_t)(b * KK + i) * KK + tid] = hok * sel_ok[b * 2 * KK + KK + tid];
    }
}

// ---------------------------------------------------------------------------
extern "C" void kernel_launch(void* const* d_in, const int* in_sizes, int n_in,
                              void* d_out, int out_size, void* d_ws, size_t ws_size,
                              hipStream_t stream) {
    const float* feat   = (const float*)d_in[0];
    const int*   boxes  = (const int*)d_in[1];
    const int*   labels = (const int*)d_in[2];
    const float* scores = (const float*)d_in[3];
    const float* W1     = (const float*)d_in[4];
    const float* b1     = (const float*)d_in[5];
    const float* W2     = (const float*)d_in[6];
    const float* b2     = (const float*)d_in[7];
    const float* W3     = (const float*)d_in[8];
    const float* b3     = (const float*)d_in[9];

    float* ws       = (float*)d_ws;
    int*   sel_idx  = (int*)(ws + OFF_SELIDX);
    float* sel_ok   = ws + OFF_OK;
    float* inv_area = ws + OFF_INV;
    float* pooled   = ws + OFF_POOLED;
    float* part     = ws + OFF_PART;

    hipMemsetAsync(pooled, 0, sizeof(float) * 160 * Dd, stream);
    topk_kernel<<<1, 64, 0, stream>>>(labels, scores, boxes, sel_idx, sel_ok, inv_area);
    pool_kernel<<<dim3(160, 96), 192, 0, stream>>>(feat, boxes, sel_idx, pooled);
    part_kernel<<<dim3(16, 2), 256, 0, stream>>>(pooled, inv_area, W1, part);
    mlp_kernel<<<Bsz * KK, 256, 0, stream>>>(part, sel_ok, b1, W2, b2, W3, b3, (float*)d_out);
}

// Round 5
// 535.119 us; speedup vs baseline: 1.4494x; 1.0918x over previous
//
#include <hip/hip_runtime.h>
#include <math.h>

#define Bsz 8
#define NBOX 100
#define Hh 96
#define Ww 96
#define Dd 768
#define KK 10
#define C1 512
#define C2 256
#define C3 117
#define NCHUNK 48   // 2 feature rows per partial chunk

// workspace layout (in floats)
#define OFF_SELIDX 0                    // 160 ints
#define OFF_OK     160                  // 160 floats
#define OFF_INV    320                  // 160 floats
#define OFF_PART   512                  // 160*512 floats
#define OFF_PARTIAL (512 + 160*C1)      // 160*48*768 floats (16B-aligned: 82432%4==0)

// ---------------------------------------------------------------------------
// Kernel A: top-K per (batch, category). 16 waves in one block; each wave
// runs K rounds of a 64-lane shuffle-butterfly argmax over its masked score
// row in LDS (tie-break: lowest index, matching jax.lax.top_k).
// ---------------------------------------------------------------------------
__global__ void topk_kernel(const int* __restrict__ labels,
                            const float* __restrict__ scores,
                            const int* __restrict__ boxes,
                            int* __restrict__ sel_idx,
                            float* __restrict__ sel_ok,
                            float* __restrict__ inv_area) {
    __shared__ float arr[16][NBOX];
    int tid = threadIdx.x;
    for (int idx = tid; idx < 16 * NBOX; idx += 1024) {
        int t = idx / NBOX, n = idx - t * NBOX;
        int b = t >> 1, c = t & 1;
        int lab = labels[b * NBOX + n];
        bool keep = (c == 0) ? (lab == 1) : (lab != 1);
        arr[t][n] = keep ? scores[b * NBOX + n] : -1e30f;
    }
    __syncthreads();
    int w = tid >> 6, lane = tid & 63;
    int b = w >> 1;
    for (int k = 0; k < KK; ++k) {
        float bv = arr[w][lane]; int bi = lane;          // lane 0..63 < 100
        if (lane + 64 < NBOX) {
            float v = arr[w][lane + 64];
            if (v > bv) { bv = v; bi = lane + 64; }      // idx lane+64 > lane: > only
        }
#pragma unroll
        for (int off = 32; off >= 1; off >>= 1) {
            float ov = __shfl_xor(bv, off);
            int   oi = __shfl_xor(bi, off);
            if (ov > bv || (ov == bv && oi < bi)) { bv = ov; bi = oi; }
        }
        if (lane == 0) {
            arr[w][bi] = -INFINITY;
            int s = w * KK + k;
            sel_idx[s] = bi;
            sel_ok[s] = (bv > -5e29f) ? 1.0f : 0.0f;
            const int* bx = boxes + (b * NBOX + bi) * 4;
            inv_area[s] = 1.0f / (float)((bx[3] - bx[1]) * (bx[2] - bx[0]));
        }
        __syncthreads();
    }
}

// ---------------------------------------------------------------------------
// Kernel B: box-sum pooling of the 160 selected boxes, NO atomics.
// One block per (box, 2-row chunk): grid (160, 48). 192 threads own one
// float4 channel group; x-loop 4-way unrolled (16 outstanding loads).
// Every block stores its partial (zeros if the chunk is outside the box),
// so the partial buffer needs no pre-zeroing and no poison survives.
// ---------------------------------------------------------------------------
__global__ void pool_kernel(const float* __restrict__ feat,
                            const int* __restrict__ boxes,
                            const int* __restrict__ sel_idx,
                            float* __restrict__ partial) {
    int s = blockIdx.x, yc = blockIdx.y;
    int b = s / (2 * KK);
    int n = sel_idx[s];
    const int* bx = boxes + (b * NBOX + n) * 4;
    int x1 = bx[0], y1 = bx[1], x2 = bx[2], y2 = bx[3];
    int d4 = threadIdx.x;                       // 0..191
    float4 a0 = make_float4(0.f, 0.f, 0.f, 0.f);
    float4 a1 = a0, a2 = a0, a3 = a0;
    int y0 = y1 + 2 * yc;
    if (y0 < y2) {
        int ye = min(y0 + 2, y2);
        const float4* feat4 = (const float4*)feat;
        for (int y = y0; y < ye; ++y) {
            const float4* rowp = feat4 + ((size_t)(b * Hh + y) * Ww) * (Dd / 4) + d4;
            int x = x1;
            for (; x + 4 <= x2; x += 4) {
                float4 v0 = rowp[(size_t)(x + 0) * (Dd / 4)];
                float4 v1 = rowp[(size_t)(x + 1) * (Dd / 4)];
                float4 v2 = rowp[(size_t)(x + 2) * (Dd / 4)];
                float4 v3 = rowp[(size_t)(x + 3) * (Dd / 4)];
                a0.x += v0.x; a0.y += v0.y; a0.z += v0.z; a0.w += v0.w;
                a1.x += v1.x; a1.y += v1.y; a1.z += v1.z; a1.w += v1.w;
                a2.x += v2.x; a2.y += v2.y; a2.z += v2.z; a2.w += v2.w;
                a3.x += v3.x; a3.y += v3.y; a3.z += v3.z; a3.w += v3.w;
            }
            for (; x < x2; ++x) {
                float4 v0 = rowp[(size_t)x * (Dd / 4)];
                a0.x += v0.x; a0.y += v0.y; a0.z += v0.z; a0.w += v0.w;
            }
        }
        a0.x += a1.x + a2.x + a3.x;
        a0.y += a1.y + a2.y + a3.y;
        a0.z += a1.z + a2.z + a3.z;
        a0.w += a1.w + a2.w + a3.w;
    }
    ((float4*)partial)[((size_t)s * NCHUNK + yc) * (Dd / 4) + d4] = a0;
}

// ---------------------------------------------------------------------------
// Kernel C: reduce partials -> LDS, then per-slot half-projection through W1
// (layer-1 decomposes over the concat: pair@W1 = h@W1_top + o@W1_bot).
// ---------------------------------------------------------------------------
__global__ void part_kernel(const float* __restrict__ partial,
                            const float* __restrict__ inv_area,
                            const float* __restrict__ W1,
                            float* __restrict__ part) {
    __shared__ float pv[KK * Dd];                 // 30 KB: 10 slots' raw sums
    int sg = blockIdx.x;                          // 0..15 (= b*2 + c)
    int o = blockIdx.y * 256 + threadIdx.x;       // 0..511
    const float4* p4 = (const float4*)partial;
    float4* pv4 = (float4*)pv;
    for (int idx = threadIdx.x; idx < KK * (Dd / 4); idx += 256) {
        int j = idx / (Dd / 4), d4 = idx - j * (Dd / 4);
        const float4* src = p4 + ((size_t)(sg * KK + j) * NCHUNK) * (Dd / 4) + d4;
        float4 acc = make_float4(0.f, 0.f, 0.f, 0.f);
        for (int yc = 0; yc < NCHUNK; ++yc) {
            float4 v = src[(size_t)yc * (Dd / 4)];
            acc.x += v.x; acc.y += v.y; acc.z += v.z; acc.w += v.w;
        }
        pv4[idx] = acc;
    }
    __syncthreads();
    int c = sg & 1;
    const float* Wp = W1 + (size_t)(c * Dd) * C1 + o;
    float acc[KK];
#pragma unroll
    for (int j = 0; j < KK; ++j) acc[j] = 0.f;
    for (int d = 0; d < Dd; ++d) {
        float w = Wp[(size_t)d * C1];
#pragma unroll
        for (int j = 0; j < KK; ++j) acc[j] += pv[j * Dd + d] * w;
    }
    for (int j = 0; j < KK; ++j)
        part[(size_t)(sg * KK + j) * C1 + o] = acc[j] * inv_area[sg * KK + j];
}

// ---------------------------------------------------------------------------
// Kernel D: fused layers 1(sum+bias+relu) -> 2 -> 3 + valid mask.
// One block per (b, human i); 10 object pairs share W2/W3 reads.
// ---------------------------------------------------------------------------
__global__ void mlp_kernel(const float* __restrict__ part,
                           const float* __restrict__ sel_ok,
                           const float* __restrict__ b1,
                           const float* __restrict__ W2,
                           const float* __restrict__ b2,
                           const float* __restrict__ W3,
                           const float* __restrict__ b3,
                           float* __restrict__ out) {
    __shared__ float x1s[KK][C1];   // 20 KB
    __shared__ float x2s[KK][C2];   // 10 KB
    int blk = blockIdx.x;
    int b = blk / KK, i = blk % KK;
    const float* hp = part + (size_t)(b * 2 * KK + i) * C1;       // human slot i
    const float* op = part + (size_t)(b * 2 * KK + KK) * C1;      // object slots base
    int tid = threadIdx.x;

    // layer 1: relu(hpart + opart + b1)
    for (int o = tid; o < C1; o += 256) {
        float h = hp[o] + b1[o];
#pragma unroll
        for (int j = 0; j < KK; ++j) {
            float v = h + op[(size_t)j * C1 + o];
            x1s[j][o] = v > 0.f ? v : 0.f;
        }
    }
    __syncthreads();

    // layer 2: 512 -> 256, relu
    {
        int o2 = tid;
        float acc[KK];
        float bb = b2[o2];
#pragma unroll
        for (int j = 0; j < KK; ++j) acc[j] = bb;
        for (int k = 0; k < C1; ++k) {
            float w = W2[(size_t)k * C2 + o2];
#pragma unroll
            for (int j = 0; j < KK; ++j) acc[j] += x1s[j][k] * w;
        }
#pragma unroll
        for (int j = 0; j < KK; ++j) x2s[j][o2] = acc[j] > 0.f ? acc[j] : 0.f;
    }
    __syncthreads();

    // layer 3: 256 -> 117, mask, store
    float* rel = out;
    float* valid = out + (size_t)Bsz * KK * KK * C3;
    float hok = sel_ok[b * 2 * KK + i];
    if (tid < C3) {
        float acc[KK];
        float bb = b3[tid];
#pragma unroll
        for (int j = 0; j < KK; ++j) acc[j] = bb;
        for (int k = 0; k < C2; ++k) {
            float w = W3[(size_t)k * C3 + tid];
#pragma unroll
            for (int j = 0; j < KK; ++j) acc[j] += x2s[j][k] * w;
        }
        for (int j = 0; j < KK; ++j) {
            float v = hok * sel_ok[b * 2 * KK + KK + j];
            rel[((size_t)(b * KK + i) * KK + j) * C3 + tid] = acc[j] * v;
        }
    }
    if (tid < KK) {
        valid[(size_t)(b * KK + i) * KK + tid] = hok * sel_ok[b * 2 * KK + KK + tid];
    }
}

// ---------------------------------------------------------------------------
extern "C" void kernel_launch(void* const* d_in, const int* in_sizes, int n_in,
                              void* d_out, int out_size, void* d_ws, size_t ws_size,
                              hipStream_t stream) {
    const float* feat   = (const float*)d_in[0];
    const int*   boxes  = (const int*)d_in[1];
    const int*   labels = (const int*)d_in[2];
    const float* scores = (const float*)d_in[3];
    const float* W1     = (const float*)d_in[4];
    const float* b1     = (const float*)d_in[5];
    const float* W2     = (const float*)d_in[6];
    const float* b2     = (const float*)d_in[7];
    const float* W3     = (const float*)d_in[8];
    const float* b3     = (const float*)d_in[9];

    float* ws       = (float*)d_ws;
    int*   sel_idx  = (int*)(ws + OFF_SELIDX);
    float* sel_ok   = ws + OFF_OK;
    float* inv_area = ws + OFF_INV;
    float* part     = ws + OFF_PART;
    float* partial  = ws + OFF_PARTIAL;

    topk_kernel<<<1, 1024, 0, stream>>>(labels, scores, boxes, sel_idx, sel_ok, inv_area);
    pool_kernel<<<dim3(160, NCHUNK), 192, 0, stream>>>(feat, boxes, sel_idx, partial);
    part_kernel<<<dim3(16, 2), 256, 0, stream>>>(partial, inv_area, W1, part);
    mlp_kernel<<<Bsz * KK, 256, 0, stream>>>(part, sel_ok, b1, W2, b2, W3, b3, (float*)d_out);
}